// Round 5
// baseline (157.878 us; speedup 1.0000x reference)
//
#include <hip/hip_runtime.h>
#include <hip/hip_bf16.h>
#include <math.h>

typedef __attribute__((ext_vector_type(8))) short s16x8;
typedef __attribute__((ext_vector_type(4))) float f32x4;
typedef __attribute__((ext_vector_type(2))) float v2f;

__device__ __forceinline__ unsigned short f2bf(float f) {
    union { float f; unsigned int u; } v; v.f = f;
    unsigned int u = v.u + 0x7FFFu + ((v.u >> 16) & 1u);
    return (unsigned short)(u >> 16);
}
__device__ __forceinline__ unsigned pk2(float lo, float hi) {
    __hip_bfloat162 h = __float22bfloat162_rn(make_float2(lo, hi));
    union { __hip_bfloat162 h; unsigned u; } v; v.h = h;
    return v.u;
}
// unpack uint (2 bf16) -> float2 {lo, hi}
__device__ __forceinline__ v2f up2(unsigned u) {
    union { unsigned u; float f; } a, b;
    a.u = u << 16; b.u = u & 0xffff0000u;
    v2f r; r.x = a.f; r.y = b.f; return r;
}

// blend 4 corner uint4s with packed-f32 math, store packed bf16 uint4 to LDS
__device__ __forceinline__ void blend4(uint4 uA, uint4 uB, uint4 uC, uint4 uD,
                                       v2f c00, v2f c01, v2f c10, v2f c11,
                                       unsigned short* dst) {
    unsigned ua[4] = {uA.x, uA.y, uA.z, uA.w};
    unsigned ub[4] = {uB.x, uB.y, uB.z, uB.w};
    unsigned uc[4] = {uC.x, uC.y, uC.z, uC.w};
    unsigned ud[4] = {uD.x, uD.y, uD.z, uD.w};
    unsigned pk[4];
#pragma unroll
    for (int i = 0; i < 4; ++i) {
        v2f r = c00 * up2(ua[i]) + c01 * up2(ub[i]) + c10 * up2(uc[i]) + c11 * up2(ud[i]);
        pk[i] = pk2(r.x, r.y);
    }
    *(uint4*)dst = make_uint4(pk[0], pk[1], pk[2], pk[3]);
}

// ============ Fused prep kernel (block-specialized, verified R4) ============
__global__ __launch_bounds__(256) void k_prep(const float* __restrict__ x,
                                              const float* __restrict__ lat,
                                              const float* __restrict__ tw,
                                              const float* __restrict__ w1,
                                              const float* __restrict__ b1,
                                              const float* __restrict__ w2,
                                              const float* __restrict__ b2,
                                              unsigned short* __restrict__ xp,
                                              unsigned short* __restrict__ A2f,
                                              unsigned short* __restrict__ Awf,
                                              int* __restrict__ ipar,
                                              float* __restrict__ fpar) {
    __shared__ float sm[8420];
    int b = blockIdx.x, t = threadIdx.x;
    if (b == 0) {
        for (int i = t; i < 8192; i += 256) sm[(i >> 7) * 129 + (i & 127)] = w1[i * 9 + 4];
        __syncthreads();
        if (t < 128) {
            int n = t >> 6, o = t & 63;
            float s = b1[o];
            const float* ln = lat + n * 128;
#pragma unroll 8
            for (int c = 0; c < 128; ++c) s += ln[c] * sm[o * 129 + c];
            sm[8256 + t] = fmaxf(s, 0.f);
        }
        __syncthreads();
        if (t < 36) {
            int n = t / 18, j = t % 18;
            float s = b2[j];
            for (int o = 0; o < 64; ++o) s += sm[8256 + n * 64 + o] * w2[(j * 64 + o) * 9 + 4];
            float ov = tanhf(s);
            ov = fminf(fmaxf(ov, -0.999999f), 0.999999f);
            sm[8384 + t] = ov;
        }
        __syncthreads();
        if (t < 36) {
            int n = t / 18, j = t % 18;
            int tap = j >> 1, d = j & 1;
            float ov = sm[8384 + t];
            float fl = floorf(ov);
            int kc = d ? (tap % 3) : (tap / 3);
            ipar[(n * 9 + tap) * 2 + d] = kc - 1 + (int)fl;
            fpar[(n * 9 + tap) * 2 + d] = ov - fl;
        }
    } else if (b < 145) {
        int slot = (b - 1) * 256 + t;
        int l = slot & 63;
        int mi = (slot >> 6) & 3;
        int w = (slot >> 8) & 3;
        int k = slot >> 10;
        int row = w * 64 + mi * 16 + (l & 15);
        int kq = l >> 4;
        unsigned short v[8];
#pragma unroll
        for (int j = 0; j < 8; ++j) {
            int kcol = k * 32 + kq * 8 + j;
            int tap = kcol >> 7, c = kcol & 127;
            v[j] = f2bf(tw[(row * 128 + c) * 9 + tap]);
        }
        unsigned p0 = (unsigned)v[0] | ((unsigned)v[1] << 16);
        unsigned p1 = (unsigned)v[2] | ((unsigned)v[3] << 16);
        unsigned p2 = (unsigned)v[4] | ((unsigned)v[5] << 16);
        unsigned p3 = (unsigned)v[6] | ((unsigned)v[7] << 16);
        *(uint4*)(A2f + slot * 8) = make_uint4(p0, p1, p2, p3);
    } else if (b < 289) {
        int slot = (b - 145) * 256 + t;
        int l = slot & 63;
        int mi = (slot >> 6) & 3;
        int wm = (slot >> 8) & 1;
        int k = slot >> 9;
        int row = wm * 64 + mi * 16 + (l & 15);
        int kq = l >> 4;
        unsigned short v[8];
#pragma unroll
        for (int j = 0; j < 8; ++j) {
            int kcol = k * 32 + kq * 8 + j;
            int t9 = kcol >> 8, ci = kcol & 255;
            int ky = t9 / 3, kx = t9 - ky * 3;
            v[j] = f2bf(tw[(ci * 128 + row) * 9 + (2 - ky) * 3 + (2 - kx)]);
        }
        unsigned p0 = (unsigned)v[0] | ((unsigned)v[1] << 16);
        unsigned p1 = (unsigned)v[2] | ((unsigned)v[3] << 16);
        unsigned p2 = (unsigned)v[4] | ((unsigned)v[5] << 16);
        unsigned p3 = (unsigned)v[6] | ((unsigned)v[7] << 16);
        *(uint4*)(Awf + slot * 8) = make_uint4(p0, p1, p2, p3);
    } else {
        int bb = b - 289;
        int h = bb & 63, cq = (bb >> 6) & 3, n = bb >> 8;
        int c0 = cq * 64;
        {
            int wcol = t & 63, sub = t >> 6;
            for (int r = 0; r < 16; ++r) {
                int ci_l = r * 4 + sub;
                sm[ci_l * 65 + wcol] = x[((n * 256 + c0 + ci_l) * 64 + h) * 64 + wcol];
            }
        }
        __syncthreads();
        int wcol = t >> 2, cg = t & 3;
        unsigned short* dst = xp + (size_t)n * (65 * 65 * 256) + (h * 65 + wcol) * 256 + c0 + cg * 16;
        unsigned pk[8];
#pragma unroll
        for (int j = 0; j < 8; ++j)
            pk[j] = pk2(sm[(cg * 16 + 2 * j) * 65 + wcol], sm[(cg * 16 + 2 * j + 1) * 65 + wcol]);
        *(uint4*)dst = make_uint4(pk[0], pk[1], pk[2], pk[3]);
        *(uint4*)(dst + 8) = make_uint4(pk[4], pk[5], pk[6], pk[7]);
    }
}

// ============ tconv: barrier-free, LDS-free MFMA GEMM (per-lane B fragments) ============
// 512 blocks, heavy parity class first. Block = (class, n, yh): 4 waves x N=16 cols.
__global__ __launch_bounds__(256) void k_tconv4(const unsigned short* __restrict__ xp,
                                                const unsigned short* __restrict__ Awf,
                                                unsigned short* __restrict__ upp) {
    int t = threadIdx.x;
    int b = blockIdx.x;
    int cls = b >> 7;                       // 0:(1,1) 1:(1,0) 2:(0,1) 3:(0,0)  heavy-first
    int phase = (cls < 2) ? 1 : 0;
    int xpar = 1 - (cls & 1);
    int idx = b & 127;
    int n = idx >> 6, yh = idx & 63;
    int y = 2 * yh + phase;
    const unsigned short* xpn = xp + (size_t)n * (65 * 65 * 256);

    int lane = t & 63, w = t >> 6;
    int col = lane & 15, q = lane >> 4;
    int pos = w * 16 + col;                 // block N-position 0..63

    int nky = phase ? 2 : 1;
    int nkx = xpar ? 2 : 1;

    f32x4 acc[8];
#pragma unroll
    for (int mi = 0; mi < 8; ++mi) acc[mi] = (f32x4){0.f, 0.f, 0.f, 0.f};

    const unsigned short* Afl = Awf + lane * 8;

    for (int a1 = 0; a1 < nky; ++a1) {
        int ky = phase ? (a1 ? 2 : 0) : 1;
        int d2 = (y + ky - 1) >> 1;
        for (int a2 = 0; a2 < nkx; ++a2) {
            int kx = xpar ? (a2 ? 2 : 0) : 1;
            int s = (xpar + kx - 1) >> 1;
            int t9 = ky * 3 + kx;
            const unsigned short* bptr = xpn + ((size_t)(d2 * 65 + s + pos)) * 256 + q * 8;
            const unsigned short* aptr = Afl + t9 * 8 * 4096;
#pragma unroll 2
            for (int cb = 0; cb < 8; ++cb) {
                s16x8 bf = *(const s16x8*)(bptr + cb * 32);
                s16x8 a[8];
#pragma unroll
                for (int mi = 0; mi < 8; ++mi)
                    a[mi] = *(const s16x8*)(aptr + cb * 4096 + (mi >> 2) * 2048 + (mi & 3) * 512);
#pragma unroll
                for (int mi = 0; mi < 8; ++mi)
                    acc[mi] = __builtin_amdgcn_mfma_f32_16x16x32_bf16(a[mi], bf, acc[mi], 0, 0, 0);
            }
        }
    }

    unsigned short* uppn = upp + (size_t)n * (132 * 132 * 128);
    int xg = 2 * pos + xpar;
#pragma unroll
    for (int mi = 0; mi < 8; ++mi) {
        int co = mi * 16 + q * 4;
        unsigned short* p = uppn + ((y + 2) * 132 + (xg + 2)) * 128 + co;
        unsigned lo = pk2(acc[mi][0], acc[mi][1]);
        unsigned hi = pk2(acc[mi][2], acc[mi][3]);
        *(uint2*)p = make_uint2(lo, hi);
    }
}

// ============ deform: MFMA GEMM, chunk-pair windows, prefetched corners/A, pk-f32 blend ====
__global__ __launch_bounds__(256, 2) void k_deform4(const unsigned short* __restrict__ upp,
                                                    const unsigned short* __restrict__ A2f,
                                                    const int* __restrict__ ipar,
                                                    const float* __restrict__ fpar,
                                                    float* __restrict__ out) {
    __shared__ unsigned short Bs[2][64][84];   // pair buffer: chunk c at col c*42, 42-dword stride
    int t = threadIdx.x;
    int b = blockIdx.x;
    int xcd = b & 7, j = b >> 3;
    int n = xcd >> 2, band = xcd & 3;
    int y = band * 32 + (j & 31);
    int tx0 = (j >> 5) * 64;
    const unsigned short* uppn = upp + (size_t)n * (132 * 132 * 128);

    int lane = t & 63, w = t >> 6;
    int col = lane & 15, q = lane >> 4;
    int bx = t >> 2, bcg = t & 3;
    int boff = bx * 128 + bcg * 8;

    const int* ipn = ipar + n * 18;
    const float* fpn = fpar + n * 18;

    f32x4 acc[4][4];
#pragma unroll
    for (int mi = 0; mi < 4; ++mi)
#pragma unroll
        for (int ni = 0; ni < 4; ++ni) acc[mi][ni] = (f32x4){0.f, 0.f, 0.f, 0.f};

    const unsigned short* Afw = A2f + w * 2048 + lane * 8;   // + chunk*8192 + mi*512

    // tap-parameter fetch (wave-uniform -> scalar loads)
#define TAPP(tap, PB, C00, C01, C10, C11)                                        \
    {                                                                            \
        int iy = ipn[(tap)*2], ix = ipn[(tap)*2 + 1];                            \
        float fy = fpn[(tap)*2], fx = fpn[(tap)*2 + 1];                          \
        float w00 = (1.f - fy) * (1.f - fx), w01 = (1.f - fy) * fx;              \
        float w10 = fy * (1.f - fx), w11 = fy * fx;                              \
        C00 = (v2f){w00, w00}; C01 = (v2f){w01, w01};                            \
        C10 = (v2f){w10, w10}; C11 = (v2f){w11, w11};                            \
        PB = uppn + ((size_t)((y + 2 + iy) * 132 + (tx0 + 2 + ix))) * 128 + boff;\
    }

    const unsigned short* pb;      // corner base for prefetched pair
    v2f cN00, cN01, cN10, cN11;    // blend weights for prefetched pair
    uint4 cr[8];                   // corners for 2 chunks x 4 corners
    s16x8 a_cur[8], a_nxt[8];

    // ---- prologue: pair 0 ----
    TAPP(0, pb, cN00, cN01, cN10, cN11);
#pragma unroll
    for (int c = 0; c < 2; ++c) {
        const unsigned short* p = pb + c * 32;
        cr[c * 4 + 0] = *(const uint4*)p;
        cr[c * 4 + 1] = *(const uint4*)(p + 128);
        cr[c * 4 + 2] = *(const uint4*)(p + 16896);
        cr[c * 4 + 3] = *(const uint4*)(p + 17024);
    }
#pragma unroll
    for (int c = 0; c < 2; ++c)
#pragma unroll
        for (int mi = 0; mi < 4; ++mi)
            a_cur[c * 4 + mi] = *(const s16x8*)(Afw + c * 8192 + mi * 512);
#pragma unroll
    for (int c = 0; c < 2; ++c)
        blend4(cr[c * 4 + 0], cr[c * 4 + 1], cr[c * 4 + 2], cr[c * 4 + 3],
               cN00, cN01, cN10, cN11, &Bs[0][bx][c * 42 + bcg * 8]);
    // prefetch corners for pair 1 (same tap 0, cb 64/96)
#pragma unroll
    for (int c = 0; c < 2; ++c) {
        const unsigned short* p = pb + 64 + c * 32;
        cr[c * 4 + 0] = *(const uint4*)p;
        cr[c * 4 + 1] = *(const uint4*)(p + 128);
        cr[c * 4 + 2] = *(const uint4*)(p + 16896);
        cr[c * 4 + 3] = *(const uint4*)(p + 17024);
    }
    __syncthreads();

#pragma unroll 2
    for (int kk = 0; kk < 18; ++kk) {
        int cur = kk & 1;
        // blend pair kk+1 (corners loaded in previous window, complete after barrier)
        if (kk < 17) {
#pragma unroll
            for (int c = 0; c < 2; ++c)
                blend4(cr[c * 4 + 0], cr[c * 4 + 1], cr[c * 4 + 2], cr[c * 4 + 3],
                       cN00, cN01, cN10, cN11, &Bs[cur ^ 1][bx][c * 42 + bcg * 8]);
            // issue A loads for pair kk+1 (hidden under this window's MFMA)
#pragma unroll
            for (int c = 0; c < 2; ++c)
#pragma unroll
                for (int mi = 0; mi < 4; ++mi)
                    a_nxt[c * 4 + mi] = *(const s16x8*)(Afw + (size_t)(2 * (kk + 1) + c) * 8192 + mi * 512);
        }
        // issue corner loads for pair kk+2
        if (kk < 16) {
            int kk2 = kk + 2;
            TAPP(kk2 >> 1, pb, cN00, cN01, cN10, cN11);
            int cb0 = (kk2 & 1) ? 64 : 0;
#pragma unroll
            for (int c = 0; c < 2; ++c) {
                const unsigned short* p = pb + cb0 + c * 32;
                cr[c * 4 + 0] = *(const uint4*)p;
                cr[c * 4 + 1] = *(const uint4*)(p + 128);
                cr[c * 4 + 2] = *(const uint4*)(p + 16896);
                cr[c * 4 + 3] = *(const uint4*)(p + 17024);
            }
        }
        // MFMA pair kk
#pragma unroll
        for (int c = 0; c < 2; ++c) {
            s16x8 bbf[4];
#pragma unroll
            for (int ni = 0; ni < 4; ++ni)
                bbf[ni] = *(const s16x8*)&Bs[cur][ni * 16 + col][c * 42 + q * 8];
#pragma unroll
            for (int mi = 0; mi < 4; ++mi)
#pragma unroll
                for (int ni = 0; ni < 4; ++ni)
                    acc[mi][ni] = __builtin_amdgcn_mfma_f32_16x16x32_bf16(a_cur[c * 4 + mi], bbf[ni], acc[mi][ni], 0, 0, 0);
        }
        if (kk < 17) {
#pragma unroll
            for (int i = 0; i < 8; ++i) a_cur[i] = a_nxt[i];
        }
        __syncthreads();
    }
#undef TAPP

#pragma unroll
    for (int mi = 0; mi < 4; ++mi)
#pragma unroll
        for (int ni = 0; ni < 4; ++ni) {
            int o = w * 64 + mi * 16 + q * 4;
            int xg = tx0 + ni * 16 + col;
            float* p = out + (((size_t)(n * 256 + o)) * 128 + y) * 128 + xg;
            p[0]         = acc[mi][ni][0];
            p[16384]     = acc[mi][ni][1];
            p[2 * 16384] = acc[mi][ni][2];
            p[3 * 16384] = acc[mi][ni][3];
        }
}

extern "C" void kernel_launch(void* const* d_in, const int* in_sizes, int n_in,
                              void* d_out, int out_size, void* d_ws, size_t ws_size,
                              hipStream_t stream) {
    const float* x   = (const float*)d_in[0];
    const float* lat = (const float*)d_in[1];
    const float* tw  = (const float*)d_in[2];
    const float* w1  = (const float*)d_in[3];
    const float* b1  = (const float*)d_in[4];
    const float* w2  = (const float*)d_in[5];
    const float* b2  = (const float*)d_in[6];
    float* out = (float*)d_out;

    char* ws = (char*)d_ws;
    unsigned short* upp = (unsigned short*)ws;                   // 8,921,088 B
    unsigned short* xp  = (unsigned short*)(ws + 8921088);       // 4,326,400 B
    unsigned short* A2f = (unsigned short*)(ws + 13247488);      //   589,824 B
    unsigned short* Awf = (unsigned short*)(ws + 13837312);      //   589,824 B
    int*   ipar         = (int*)(ws + 14427136);
    float* fpar         = (float*)(ws + 14427424);

    hipMemsetAsync(ws, 0, 13247488, stream);   // zero upp + xp (pads)
    k_prep<<<801, 256, 0, stream>>>(x, lat, tw, w1, b1, w2, b2, xp, A2f, Awf, ipar, fpar);
    k_tconv4<<<512, 256, 0, stream>>>(xp, Awf, upp);
    k_deform4<<<512, 256, 0, stream>>>(upp, A2f, ipar, fpar, out);
}